// Round 12
// baseline (490.424 us; speedup 1.0000x reference)
//
#include <hip/hip_runtime.h>

#define NNODES 100000
#define NEDGES 3200000
#define NF 13
#define NFP 16       // padded bf16 row stride for x
#define NG 512
#define BN_EPS 1e-5f
#define NTILES (NNODES / 16)   // 6250 exactly
#define CAP 80       // padded CSR slots per node (round16(deg) <= 80 for deg <= 80)

#define BSH 9                          // bucket = 512 dst nodes
#define NBUCK ((NNODES + 511) / 512)   // 196
#define RCAP 18500                     // pairs per bucket (mean 16384, sigma ~128)
#define PTILE 4096
#define NPBLK ((NEDGES + PTILE - 1) / PTILE)  // 782

#define NCHUNK ((NNODES + 63) / 64)    // 1563 64-node chunks
#define NPTASK (3 * NCHUNK)            // wave-tasks for pooling

typedef __attribute__((ext_vector_type(8))) short bf16x8;
typedef __attribute__((ext_vector_type(4))) float f32x4;

__device__ __forceinline__ float bf2f(unsigned short u) {
    return __uint_as_float(((unsigned)u) << 16);
}
__device__ __forceinline__ unsigned short f2bf(float f) {
    unsigned u = __float_as_uint(f);
    unsigned r = (u + 0x7FFFu + ((u >> 16) & 1u)) >> 16;  // RNE
    return (unsigned short)r;
}

// ---------------- phase A: partition edges into 196 buckets of 512 dst nodes ----------
__launch_bounds__(256)
__global__ void partition_kernel(const int* __restrict__ src, const int* __restrict__ dst,
                                 int* __restrict__ gcount, int* __restrict__ pairbuf) {
    __shared__ int lhist[NBUCK];
    __shared__ int lbase[NBUCK];
    __shared__ int lpos[NBUCK];
    int t = threadIdx.x;
    int base = blockIdx.x * PTILE;
    int cnt = NEDGES - base; if (cnt > PTILE) cnt = PTILE;

    int v[PTILE / 256], b[PTILE / 256];
#pragma unroll
    for (int j = 0; j < PTILE / 256; ++j) {
        int i = t + j * 256;
        if (i < cnt) {
            int d = __builtin_nontemporal_load(dst + base + i);
            int s = __builtin_nontemporal_load(src + base + i);
            b[j] = d >> BSH;
            v[j] = ((d & 511) << 17) | s;
        } else b[j] = -1;
    }
    if (t < NBUCK) lhist[t] = 0;
    __syncthreads();
#pragma unroll
    for (int j = 0; j < PTILE / 256; ++j)
        if (b[j] >= 0) atomicAdd(&lhist[b[j]], 1);
    __syncthreads();
    if (t < NBUCK) {
        lbase[t] = atomicAdd(&gcount[t], lhist[t]);
        lpos[t] = 0;
    }
    __syncthreads();
#pragma unroll
    for (int j = 0; j < PTILE / 256; ++j) {
        if (b[j] >= 0) {
            int p = atomicAdd(&lpos[b[j]], 1);
            pairbuf[(size_t)b[j] * RCAP + lbase[b[j]] + p] = v[j];
        }
    }
}

// ---------------- phase B: per-bucket scatter with LDS cursors ----------------
// Pads each node's slots to a multiple of 16 with sentinel index NNODES (zero row),
// and publishes the ROUNDED end in cursor -> agg loops are branch-free.
__launch_bounds__(512)
__global__ void bucket_scatter_kernel(const int* __restrict__ pairbuf,
                                      const int* __restrict__ gcount,
                                      int* __restrict__ cursor, int* __restrict__ csr) {
    __shared__ int lcnt[512];
    int bk = blockIdx.x;
    int lo = bk << BSH;
    int cnt = gcount[bk];
    if (threadIdx.x < 512) lcnt[threadIdx.x] = 0;
    __syncthreads();
    const int* pb = pairbuf + (size_t)bk * RCAP;
    for (int i = threadIdx.x; i < cnt; i += 512) {
        int p = pb[i];
        int s = p & 0x1FFFF;
        int dl = p >> 17;
        int pos = atomicAdd(&lcnt[dl], 1);
        csr[(size_t)(lo + dl) * CAP + pos] = s;
    }
    __syncthreads();
    int n = lo + threadIdx.x;
    if (threadIdx.x < 512 && n < NNODES) {
        int c = lcnt[threadIdx.x];
        int rc = (c + 15) & ~15;
        for (int p = c; p < rc; ++p) csr[(size_t)n * CAP + p] = NNODES;  // sentinel
        cursor[n] = n * CAP + rc;
    }
}

// ---------------- convert x (fp32, stride 13) -> xbf (bf16, stride 16, zero-padded) ---
__global__ void cvt_x_kernel(const float* __restrict__ x, unsigned short* __restrict__ xbf) {
    const int total = NNODES * NFP;
    int idx = blockIdx.x * blockDim.x + threadIdx.x;
    int stride = gridDim.x * blockDim.x;
    for (int i = idx; i < total; i += stride) {
        int n = i >> 4;
        int f = i & 15;
        xbf[i] = (f < NF) ? f2bf(x[n * NF + f]) : (unsigned short)0;
    }
}

// ---------------- zero the sentinel rows (index NNODES) of xbf, h1, h2 ----------------
__global__ void zero_sentinel_kernel(unsigned short* __restrict__ xbf,
                                     unsigned short* __restrict__ h1,
                                     unsigned short* __restrict__ h2) {
    int t = threadIdx.x;
    if (t < 16) xbf[(size_t)NNODES * NFP + t] = 0;
    else if (t < 80) h1[(size_t)NNODES * 64 + (t - 16)] = 0;
    else if (t < 144) h2[(size_t)NNODES * 64 + (t - 80)] = 0;
}

// ---------------- build MFMA B-fragments for all layer weights (bf16) ----------------
__global__ void build_frags_kernel(const float* __restrict__ w10, const float* __restrict__ w20,
                                   const float* __restrict__ w11, const float* __restrict__ w21,
                                   const float* __restrict__ w12, const float* __restrict__ w22,
                                   unsigned short* __restrict__ wfrag) {
    int tid = blockIdx.x * blockDim.x + threadIdx.x;  // 3072 total
    if (tid >= 3072) return;
    int layer = tid >> 10;
    int rem = tid & 1023;
    int mat = rem >> 9;
    int tile = (rem >> 7) & 3;
    int chunk = (rem >> 6) & 1;
    int lane = rem & 63;
    int quad = lane >> 4, n = lane & 15;
    const float* W = (layer == 0) ? (mat ? w20 : w10)
                   : (layer == 1) ? (mat ? w21 : w11)
                                  : (mat ? w22 : w12);
    int K = (layer == 0 && mat == 0) ? NF : 64;
    unsigned short* o = wfrag + ((size_t)tid) * 8;
#pragma unroll
    for (int j = 0; j < 8; ++j) {
        int k = chunk * 32 + quad * 8 + j;
        float val = (k < K) ? W[k * 64 + tile * 16 + n] : 0.f;
        o[j] = f2bf(val);
    }
}

// ---------------- branch-free vectorized bf16 aggregation (sentinel-padded CSR) -------
// One wave per node. RL lanes x ushort4 cover one row; EPG = 64/RL edges per gather.
// cursor[n] is pre-rounded to a multiple of 16 edges; padded slots index the zero row.
template <int FSTR, int RL, int PADZ>
__launch_bounds__(256, 8)
__global__ void agg_vec_kernel(const unsigned short* __restrict__ xin,
                               const int* __restrict__ cursor,
                               const int* __restrict__ csr,
                               unsigned short* __restrict__ y) {
    const int EPG = 64 / RL;      // edges per gather (L1: 16, L2/3: 4)
    const int GPI = 16 / EPG;     // gathers per 16-edge iteration (L1: 1, L2/3: 4)
    int lane = threadIdx.x & 63;
    int g = lane / RL;
    int r = lane % RL;
    int wave = (blockIdx.x * blockDim.x + threadIdx.x) >> 6;
    int nw = (gridDim.x * blockDim.x) >> 6;

    for (int n = wave; n < NNODES; n += nw) {
        int beg = n * CAP;
        int end = cursor[n];      // rounded to multiple of 16
        float ax = 0.f, ay = 0.f, az = 0.f, aw = 0.f;
        if (g == 0) {  // self row, added once
            ushort4 u = *(const ushort4*)&xin[n * FSTR + r * 4];
            ax = bf2f(u.x); ay = bf2f(u.y); az = bf2f(u.z); aw = bf2f(u.w);
        }
        for (int j = beg; j < end; j += 16) {
#pragma unroll
            for (int t = 0; t < GPI; ++t) {
                int e = j + t * EPG + g;
                int i0 = csr[e];
                ushort4 u = *(const ushort4*)&xin[i0 * FSTR + r * 4];
                ax += bf2f(u.x); ay += bf2f(u.y); az += bf2f(u.z); aw += bf2f(u.w);
            }
        }
#pragma unroll
        for (int m = RL; m < 64; m <<= 1) {
            ax += __shfl_xor(ax, m, 64);
            ay += __shfl_xor(ay, m, 64);
            az += __shfl_xor(az, m, 64);
            aw += __shfl_xor(aw, m, 64);
        }
        if (g == 0) {
            ushort4 o;
            o.x = f2bf(ax); o.y = f2bf(ay); o.z = f2bf(az); o.w = f2bf(aw);
            *(ushort4*)&y[n * 64 + r * 4] = o;
        } else if (PADZ && g == 1) {
            ushort4 o; o.x = 0; o.y = 0; o.z = 0; o.w = 0;
            *(ushort4*)&y[n * 64 + 16 + r * 4] = o;
        }
    }
}

// ---------------- MFMA MLP: 16-node tile per wave --------------------------------------
template <int KC1>
__launch_bounds__(256)
__global__ void mlp_mfma_kernel(const unsigned short* __restrict__ ybf,
                                const unsigned short* __restrict__ wfrag,
                                const float* __restrict__ b1, const float* __restrict__ g,
                                const float* __restrict__ be, const float* __restrict__ m,
                                const float* __restrict__ v,  const float* __restrict__ b2,
                                unsigned short* __restrict__ hout) {
    __shared__ __align__(16) unsigned short zs[4][16 * 72];  // per-wave slice, padded stride
    int lane = threadIdx.x & 63;
    int wid = threadIdx.x >> 6;
    int quad = lane >> 4;
    int n16 = lane & 15;

    const bf16x8* wf = (const bf16x8*)wfrag;
    bf16x8 w1f[4][2], w2f[4][2];
#pragma unroll
    for (int t = 0; t < 4; ++t) {
#pragma unroll
        for (int c = 0; c < 2; ++c) {
            w1f[t][c] = wf[((0 * 4 + t) * 2 + c) * 64 + lane];
            w2f[t][c] = wf[((1 * 4 + t) * 2 + c) * 64 + lane];
        }
    }
    float scaleF[4], shiftF[4], b2F[4];
#pragma unroll
    for (int t = 0; t < 4; ++t) {
        int f = t * 16 + n16;
        float sc = g[f] * rsqrtf(v[f] + BN_EPS);
        scaleF[t] = sc;
        shiftF[t] = (b1[f] - m[f]) * sc + be[f];
        b2F[t] = b2[f];
    }

    unsigned short* zrow = &zs[wid][0];
    int ntiles = gridDim.x * 4;
    for (int tile = blockIdx.x * 4 + wid; tile < NTILES; tile += ntiles) {
        int nodebase = tile * 16;
        const unsigned short* yrow = ybf + (size_t)(nodebase + n16) * 64 + quad * 8;
        bf16x8 a0 = *(const bf16x8*)yrow;
        bf16x8 a1 = (KC1 == 2) ? *(const bf16x8*)(yrow + 32) : a0;

        f32x4 acc[4];
#pragma unroll
        for (int t = 0; t < 4; ++t) {
            f32x4 z4 = {0.f, 0.f, 0.f, 0.f};
            z4 = __builtin_amdgcn_mfma_f32_16x16x32_bf16(a0, w1f[t][0], z4, 0, 0, 0);
            if (KC1 == 2)
                z4 = __builtin_amdgcn_mfma_f32_16x16x32_bf16(a1, w1f[t][1], z4, 0, 0, 0);
            acc[t] = z4;
        }
#pragma unroll
        for (int t = 0; t < 4; ++t) {
#pragma unroll
            for (int r = 0; r < 4; ++r) {
                float z = fmaxf(fmaf(acc[t][r], scaleF[t], shiftF[t]), 0.f);
                zrow[(quad * 4 + r) * 72 + t * 16 + n16] = f2bf(z);
            }
        }
        __threadfence_block();
        bf16x8 az0 = *(const bf16x8*)&zrow[n16 * 72 + quad * 8];
        bf16x8 az1 = *(const bf16x8*)&zrow[n16 * 72 + 32 + quad * 8];

        f32x4 acc2[4];
#pragma unroll
        for (int t = 0; t < 4; ++t) {
            f32x4 z4 = {0.f, 0.f, 0.f, 0.f};
            z4 = __builtin_amdgcn_mfma_f32_16x16x32_bf16(az0, w2f[t][0], z4, 0, 0, 0);
            z4 = __builtin_amdgcn_mfma_f32_16x16x32_bf16(az1, w2f[t][1], z4, 0, 0, 0);
            acc2[t] = z4;
        }
#pragma unroll
        for (int t = 0; t < 4; ++t) {
#pragma unroll
            for (int r = 0; r < 4; ++r) {
                float h = fmaxf(acc2[t][r] + b2F[t], 0.f);
                hout[(size_t)(nodebase + quad * 4 + r) * 64 + t * 16 + n16] = f2bf(h);
            }
        }
        __threadfence_block();
    }
}

// ---------------- pooling: one wave per (layer, 64-node chunk) ----------------
__launch_bounds__(256)
__global__ void pool_kernel(const unsigned short* __restrict__ h1,
                            const unsigned short* __restrict__ h2,
                            const unsigned short* __restrict__ h3,
                            const int* __restrict__ batch,
                            float* __restrict__ pool) {
    int task = blockIdx.x * 4 + (threadIdx.x >> 6);
    if (task >= NPTASK) return;
    int lane = threadIdx.x & 63;
    int layer = task / NCHUNK;
    int c = task - layer * NCHUNK;
    int n0 = c * 64;
    int n1 = n0 + 64; if (n1 > NNODES) n1 = NNODES;
    const unsigned short* hb = (layer == 0) ? h1 : (layer == 1) ? h2 : h3;
    float acc = 0.f;
    int curg = batch[n0];
    for (int n = n0; n < n1; ++n) {
        int gid = batch[n];
        if (gid != curg) {
            atomicAdd(&pool[(size_t)curg * 192 + layer * 64 + lane], acc);
            acc = 0.f;
            curg = gid;
        }
        acc += bf2f(hb[(size_t)n * 64 + lane]);
    }
    atomicAdd(&pool[(size_t)curg * 192 + layer * 64 + lane], acc);
}

// ---------------- FC head on pooled features ----------------
__global__ void head_kernel(const float* __restrict__ pool,
                            const float* __restrict__ fc1W, const float* __restrict__ fc1b,
                            const float* __restrict__ fc2W, const float* __restrict__ fc2b,
                            float* __restrict__ out) {
    __shared__ float ps[192];
    __shared__ float hs[192];
    int gi = blockIdx.x;
    int t = threadIdx.x;  // 192
    ps[t] = pool[gi * 192 + t];
    __syncthreads();
    float acc = fc1b[t];
#pragma unroll 8
    for (int k = 0; k < 192; ++k) acc = fmaf(ps[k], fc1W[k * 192 + t], acc);
    hs[t] = fmaxf(acc, 0.f);
    __syncthreads();
    if (t == 0) {
        float l0 = fc2b[0], l1 = fc2b[1];
        for (int k = 0; k < 192; ++k) {
            float h = hs[k];
            l0 = fmaf(h, fc2W[k * 2 + 0], l0);
            l1 = fmaf(h, fc2W[k * 2 + 1], l1);
        }
        float mx = fmaxf(l0, l1);
        float lse = mx + logf(expf(l0 - mx) + expf(l1 - mx));
        out[gi * 2 + 0] = l0 - lse;
        out[gi * 2 + 1] = l1 - lse;
    }
}

extern "C" void kernel_launch(void* const* d_in, const int* in_sizes, int n_in,
                              void* d_out, int out_size, void* d_ws, size_t ws_size,
                              hipStream_t stream) {
    const float* x = (const float*)d_in[0];
    const int* src = (const int*)d_in[1];
    const int* dst = (const int*)d_in[2];
    const int* batch = (const int*)d_in[3];
    const float* c1[8];
    const float* c2[8];
    const float* c3[8];
    for (int i = 0; i < 8; ++i) {
        c1[i] = (const float*)d_in[4 + i];
        c2[i] = (const float*)d_in[12 + i];
        c3[i] = (const float*)d_in[20 + i];
    }
    const float* fc1W = (const float*)d_in[28];
    const float* fc1b = (const float*)d_in[29];
    const float* fc2W = (const float*)d_in[30];
    const float* fc2b = (const float*)d_in[31];
    float* out = (float*)d_out;

    // ---- workspace layout (bf16 activations; xbf/h1/h2 have a sentinel zero row) ----
    unsigned short* base = (unsigned short*)d_ws;
    const size_t NA = (size_t)NNODES * 64;
    unsigned short* ybf = base;                            // N*64
    unsigned short* xbf = ybf + NA;                        // (N+1)*16
    unsigned short* h1  = xbf + (size_t)(NNODES + 1) * NFP;  // (N+1)*64
    unsigned short* h2  = h1 + NA + 64;                    // (N+1)*64
    unsigned short* h3  = h2 + NA + 64;                    // N*64
    unsigned short* wfrag = h3 + NA;                       // 3*8192 (16B-aligned)
    float* pool = (float*)(wfrag + 3 * 8192);              // G*192 fp32
    int* ibase = (int*)(pool + (size_t)NG * 192);
    int* cursor  = ibase;                             // N
    int* gcount  = ibase + NNODES;                    // NBUCK
    int* csr     = gcount + NBUCK;                    // N*CAP (+pad)
    int* pairbuf = csr + (size_t)NNODES * CAP + 256;  // NBUCK*RCAP

    hipMemsetAsync(gcount, 0, NBUCK * sizeof(int), stream);
    hipMemsetAsync(pool, 0, (size_t)NG * 192 * sizeof(float), stream);

    // ---- build padded CSR via 2-phase bucket partition + LDS-cursor scatter ----
    cvt_x_kernel<<<2048, 256, 0, stream>>>(x, xbf);
    zero_sentinel_kernel<<<1, 256, 0, stream>>>(xbf, h1, h2);
    build_frags_kernel<<<12, 256, 0, stream>>>(c1[0], c1[6], c2[0], c2[6], c3[0], c3[6], wfrag);
    partition_kernel<<<NPBLK, 256, 0, stream>>>(src, dst, gcount, pairbuf);
    bucket_scatter_kernel<<<NBUCK, 512, 0, stream>>>(pairbuf, gcount, cursor, csr);

    const int AGG_BLOCKS = 25000;  // 4 waves/block -> one wave per node
    const int MLP_BLOCKS = 1563;   // ~1 tile per wave

    // ---- layer 1 (fin=13, 32 B rows): 16 edges/gather; MFMA MLP with K=32 (1 chunk) ----
    agg_vec_kernel<NFP, 4, 1><<<AGG_BLOCKS, 256, 0, stream>>>(xbf, cursor, csr, ybf);
    mlp_mfma_kernel<1><<<MLP_BLOCKS, 256, 0, stream>>>(
        ybf, wfrag + 0 * 8192, c1[1], c1[2], c1[3], c1[4], c1[5], c1[7], h1);

    // ---- layer 2 (fin=64, 128 B rows): 4 edges/gather x4 in flight; MFMA MLP K=64 ----
    agg_vec_kernel<64, 16, 0><<<AGG_BLOCKS, 256, 0, stream>>>(h1, cursor, csr, ybf);
    mlp_mfma_kernel<2><<<MLP_BLOCKS, 256, 0, stream>>>(
        ybf, wfrag + 1 * 8192, c2[1], c2[2], c2[3], c2[4], c2[5], c2[7], h2);

    // ---- layer 3 (fin=64) ----
    agg_vec_kernel<64, 16, 0><<<AGG_BLOCKS, 256, 0, stream>>>(h2, cursor, csr, ybf);
    mlp_mfma_kernel<2><<<MLP_BLOCKS, 256, 0, stream>>>(
        ybf, wfrag + 2 * 8192, c3[1], c3[2], c3[3], c3[4], c3[5], c3[7], h3);

    // ---- pooling (one wave per layer-chunk) + FC head ----
    pool_kernel<<<(NPTASK + 3) / 4, 256, 0, stream>>>(h1, h2, h3, batch, pool);
    head_kernel<<<NG, 192, 0, stream>>>(pool, fc1W, fc1b, fc2W, fc2b, out);
}

// Round 13
// 406.985 us; speedup vs baseline: 1.2050x; 1.2050x over previous
//
#include <hip/hip_runtime.h>

#define NNODES 100000
#define NEDGES 3200000
#define NF 13
#define NFP 16       // padded bf16 row stride for x
#define NG 512
#define BN_EPS 1e-5f
#define NTILES (NNODES / 16)   // 6250 exactly
#define CAP 72       // padded CSR slots per node (deg ~ Poisson(32); P(deg>72) ~ 1e-9)

#define BSH 9                          // bucket = 512 dst nodes
#define NBUCK ((NNODES + 511) / 512)   // 196
#define RCAP 18500                     // pairs per bucket (mean 16384, sigma ~128)
#define PTILE 4096
#define NPBLK ((NEDGES + PTILE - 1) / PTILE)  // 782

#define NCHUNK ((NNODES + 63) / 64)    // 1563 64-node chunks
#define NPTASK (3 * NCHUNK)            // wave-tasks for pooling

typedef __attribute__((ext_vector_type(8))) short bf16x8;
typedef __attribute__((ext_vector_type(4))) float f32x4;

__device__ __forceinline__ float bf2f(unsigned short u) {
    return __uint_as_float(((unsigned)u) << 16);
}
__device__ __forceinline__ unsigned short f2bf(float f) {
    unsigned u = __float_as_uint(f);
    unsigned r = (u + 0x7FFFu + ((u >> 16) & 1u)) >> 16;  // RNE
    return (unsigned short)r;
}

// ---------------- phase A: partition edges into 196 buckets of 512 dst nodes ----------
__launch_bounds__(256)
__global__ void partition_kernel(const int* __restrict__ src, const int* __restrict__ dst,
                                 int* __restrict__ gcount, int* __restrict__ pairbuf) {
    __shared__ int lhist[NBUCK];
    __shared__ int lbase[NBUCK];
    __shared__ int lpos[NBUCK];
    int t = threadIdx.x;
    int base = blockIdx.x * PTILE;
    int cnt = NEDGES - base; if (cnt > PTILE) cnt = PTILE;

    int v[PTILE / 256], b[PTILE / 256];
#pragma unroll
    for (int j = 0; j < PTILE / 256; ++j) {
        int i = t + j * 256;
        if (i < cnt) {
            int d = __builtin_nontemporal_load(dst + base + i);
            int s = __builtin_nontemporal_load(src + base + i);
            b[j] = d >> BSH;
            v[j] = ((d & 511) << 17) | s;
        } else b[j] = -1;
    }
    if (t < NBUCK) lhist[t] = 0;
    __syncthreads();
#pragma unroll
    for (int j = 0; j < PTILE / 256; ++j)
        if (b[j] >= 0) atomicAdd(&lhist[b[j]], 1);
    __syncthreads();
    if (t < NBUCK) {
        lbase[t] = atomicAdd(&gcount[t], lhist[t]);
        lpos[t] = 0;
    }
    __syncthreads();
#pragma unroll
    for (int j = 0; j < PTILE / 256; ++j) {
        if (b[j] >= 0) {
            int p = atomicAdd(&lpos[b[j]], 1);
            pairbuf[(size_t)b[j] * RCAP + lbase[b[j]] + p] = v[j];
        }
    }
}

// ---------------- phase B: per-bucket scatter with LDS cursors ----------------
__launch_bounds__(512)
__global__ void bucket_scatter_kernel(const int* __restrict__ pairbuf,
                                      const int* __restrict__ gcount,
                                      int* __restrict__ cursor, int* __restrict__ csr) {
    __shared__ int lcnt[512];
    int bk = blockIdx.x;
    int lo = bk << BSH;
    int cnt = gcount[bk];
    if (threadIdx.x < 512) lcnt[threadIdx.x] = 0;
    __syncthreads();
    const int* pb = pairbuf + (size_t)bk * RCAP;
    for (int i = threadIdx.x; i < cnt; i += 512) {
        int p = pb[i];
        int s = p & 0x1FFFF;
        int dl = p >> 17;
        int pos = atomicAdd(&lcnt[dl], 1);
        csr[(size_t)(lo + dl) * CAP + pos] = s;
    }
    __syncthreads();
    int n = lo + threadIdx.x;
    if (threadIdx.x < 512 && n < NNODES) cursor[n] = n * CAP + lcnt[threadIdx.x];
}

// ---------------- convert x (fp32, stride 13) -> xbf (bf16, stride 16, zero-padded) ---
__global__ void cvt_x_kernel(const float* __restrict__ x, unsigned short* __restrict__ xbf) {
    const int total = NNODES * NFP;
    int idx = blockIdx.x * blockDim.x + threadIdx.x;
    int stride = gridDim.x * blockDim.x;
    for (int i = idx; i < total; i += stride) {
        int n = i >> 4;
        int f = i & 15;
        xbf[i] = (f < NF) ? f2bf(x[n * NF + f]) : (unsigned short)0;
    }
}

// ---------------- build MFMA B-fragments for all layer weights (bf16) ----------------
__global__ void build_frags_kernel(const float* __restrict__ w10, const float* __restrict__ w20,
                                   const float* __restrict__ w11, const float* __restrict__ w21,
                                   const float* __restrict__ w12, const float* __restrict__ w22,
                                   unsigned short* __restrict__ wfrag) {
    int tid = blockIdx.x * blockDim.x + threadIdx.x;  // 3072 total
    if (tid >= 3072) return;
    int layer = tid >> 10;
    int rem = tid & 1023;
    int mat = rem >> 9;
    int tile = (rem >> 7) & 3;
    int chunk = (rem >> 6) & 1;
    int lane = rem & 63;
    int quad = lane >> 4, n = lane & 15;
    const float* W = (layer == 0) ? (mat ? w20 : w10)
                   : (layer == 1) ? (mat ? w21 : w11)
                                  : (mat ? w22 : w12);
    int K = (layer == 0 && mat == 0) ? NF : 64;
    unsigned short* o = wfrag + ((size_t)tid) * 8;
#pragma unroll
    for (int j = 0; j < 8; ++j) {
        int k = chunk * 32 + quad * 8 + j;
        float val = (k < K) ? W[k * 64 + tile * 16 + n] : 0.f;
        o[j] = f2bf(val);
    }
}

// ---------------- vectorized bf16 aggregation, 8 B lanes (layer 1: 32 B rows) ---------
template <int FSTR, int RL, int UNROLL, int PADZ>
__launch_bounds__(256, 8)
__global__ void agg_vec_kernel(const unsigned short* __restrict__ xin,
                               const int* __restrict__ cursor,
                               const int* __restrict__ csr,
                               unsigned short* __restrict__ y) {
    const int EPG = 64 / RL;
    int lane = threadIdx.x & 63;
    int g = lane / RL;
    int r = lane % RL;
    int wave = (blockIdx.x * blockDim.x + threadIdx.x) >> 6;
    int nw = (gridDim.x * blockDim.x) >> 6;

    for (int n = wave; n < NNODES; n += nw) {
        int beg = n * CAP;
        int end = cursor[n];
        float ax = 0.f, ay = 0.f, az = 0.f, aw = 0.f;
        if (g == 0) {  // self row, added once
            ushort4 u = *(const ushort4*)&xin[n * FSTR + r * 4];
            ax = bf2f(u.x); ay = bf2f(u.y); az = bf2f(u.z); aw = bf2f(u.w);
        }
        int j = beg;
        const int STEP = UNROLL * EPG;
        for (; j + STEP <= end; j += STEP) {
#pragma unroll
            for (int t = 0; t < UNROLL; ++t) {
                int e = j + t * EPG + g;           // guaranteed < end
                int i0 = csr[e];
                ushort4 u = *(const ushort4*)&xin[i0 * FSTR + r * 4];
                ax += bf2f(u.x); ay += bf2f(u.y); az += bf2f(u.z); aw += bf2f(u.w);
            }
        }
        for (; j < end; j += EPG) {
            int e = j + g;
            if (e < end) {
                int i0 = csr[e];
                ushort4 u = *(const ushort4*)&xin[i0 * FSTR + r * 4];
                ax += bf2f(u.x); ay += bf2f(u.y); az += bf2f(u.z); aw += bf2f(u.w);
            }
        }
#pragma unroll
        for (int m = RL; m < 64; m <<= 1) {
            ax += __shfl_xor(ax, m, 64);
            ay += __shfl_xor(ay, m, 64);
            az += __shfl_xor(az, m, 64);
            aw += __shfl_xor(aw, m, 64);
        }
        if (g == 0) {
            ushort4 o;
            o.x = f2bf(ax); o.y = f2bf(ay); o.z = f2bf(az); o.w = f2bf(aw);
            *(ushort4*)&y[n * 64 + r * 4] = o;
        } else if (PADZ && g == 1) {
            ushort4 o; o.x = 0; o.y = 0; o.z = 0; o.w = 0;
            *(ushort4*)&y[n * 64 + 16 + r * 4] = o;
        }
    }
}

// ---------------- 16 B-lane aggregation for 64-feature layers ----------------
// RL=8 lanes x ushort8 (16 B) cover a 128 B row -> 8 edges per wave-gather.
// Half the gather/address instructions of the ushort4 version; same bytes.
__launch_bounds__(256, 8)
__global__ void agg_vec8_kernel(const unsigned short* __restrict__ xin,
                                const int* __restrict__ cursor,
                                const int* __restrict__ csr,
                                unsigned short* __restrict__ y) {
    int lane = threadIdx.x & 63;
    int g = lane >> 3;       // edge slot within gather [0,8)
    int r = lane & 7;        // row chunk: features r*8 .. r*8+7
    int wave = (blockIdx.x * blockDim.x + threadIdx.x) >> 6;
    int nw = (gridDim.x * blockDim.x) >> 6;

    for (int n = wave; n < NNODES; n += nw) {
        int beg = n * CAP;
        int end = cursor[n];
        float acc[8] = {0.f, 0.f, 0.f, 0.f, 0.f, 0.f, 0.f, 0.f};
        if (g == 0) {  // self row, added once
            bf16x8 u = *(const bf16x8*)&xin[(size_t)n * 64 + r * 8];
#pragma unroll
            for (int k = 0; k < 8; ++k) acc[k] = bf2f((unsigned short)u[k]);
        }
        int j = beg;
        for (; j + 16 <= end; j += 16) {   // two 8-edge gathers in flight
#pragma unroll
            for (int t = 0; t < 2; ++t) {
                int e = j + t * 8 + g;
                int i0 = csr[e];
                bf16x8 u = *(const bf16x8*)&xin[(size_t)i0 * 64 + r * 8];
#pragma unroll
                for (int k = 0; k < 8; ++k) acc[k] += bf2f((unsigned short)u[k]);
            }
        }
        for (; j < end; j += 8) {
            int e = j + g;
            if (e < end) {
                int i0 = csr[e];
                bf16x8 u = *(const bf16x8*)&xin[(size_t)i0 * 64 + r * 8];
#pragma unroll
                for (int k = 0; k < 8; ++k) acc[k] += bf2f((unsigned short)u[k]);
            }
        }
        // reduce across the 8 edge-groups (masks 8,16,32)
#pragma unroll
        for (int m = 8; m < 64; m <<= 1) {
#pragma unroll
            for (int k = 0; k < 8; ++k) acc[k] += __shfl_xor(acc[k], m, 64);
        }
        if (g == 0) {
            bf16x8 o;
#pragma unroll
            for (int k = 0; k < 8; ++k) o[k] = (short)f2bf(acc[k]);
            *(bf16x8*)&y[(size_t)n * 64 + r * 8] = o;
        }
    }
}

// ---------------- MFMA MLP: 16-node tile per wave --------------------------------------
template <int KC1>
__launch_bounds__(256)
__global__ void mlp_mfma_kernel(const unsigned short* __restrict__ ybf,
                                const unsigned short* __restrict__ wfrag,
                                const float* __restrict__ b1, const float* __restrict__ g,
                                const float* __restrict__ be, const float* __restrict__ m,
                                const float* __restrict__ v,  const float* __restrict__ b2,
                                unsigned short* __restrict__ hout) {
    __shared__ __align__(16) unsigned short zs[4][16 * 72];  // per-wave slice, padded stride
    int lane = threadIdx.x & 63;
    int wid = threadIdx.x >> 6;
    int quad = lane >> 4;
    int n16 = lane & 15;

    const bf16x8* wf = (const bf16x8*)wfrag;
    bf16x8 w1f[4][2], w2f[4][2];
#pragma unroll
    for (int t = 0; t < 4; ++t) {
#pragma unroll
        for (int c = 0; c < 2; ++c) {
            w1f[t][c] = wf[((0 * 4 + t) * 2 + c) * 64 + lane];
            w2f[t][c] = wf[((1 * 4 + t) * 2 + c) * 64 + lane];
        }
    }
    float scaleF[4], shiftF[4], b2F[4];
#pragma unroll
    for (int t = 0; t < 4; ++t) {
        int f = t * 16 + n16;
        float sc = g[f] * rsqrtf(v[f] + BN_EPS);
        scaleF[t] = sc;
        shiftF[t] = (b1[f] - m[f]) * sc + be[f];
        b2F[t] = b2[f];
    }

    unsigned short* zrow = &zs[wid][0];
    int ntiles = gridDim.x * 4;
    for (int tile = blockIdx.x * 4 + wid; tile < NTILES; tile += ntiles) {
        int nodebase = tile * 16;
        const unsigned short* yrow = ybf + (size_t)(nodebase + n16) * 64 + quad * 8;
        bf16x8 a0 = *(const bf16x8*)yrow;
        bf16x8 a1 = (KC1 == 2) ? *(const bf16x8*)(yrow + 32) : a0;

        f32x4 acc[4];
#pragma unroll
        for (int t = 0; t < 4; ++t) {
            f32x4 z4 = {0.f, 0.f, 0.f, 0.f};
            z4 = __builtin_amdgcn_mfma_f32_16x16x32_bf16(a0, w1f[t][0], z4, 0, 0, 0);
            if (KC1 == 2)
                z4 = __builtin_amdgcn_mfma_f32_16x16x32_bf16(a1, w1f[t][1], z4, 0, 0, 0);
            acc[t] = z4;
        }
#pragma unroll
        for (int t = 0; t < 4; ++t) {
#pragma unroll
            for (int r = 0; r < 4; ++r) {
                float z = fmaxf(fmaf(acc[t][r], scaleF[t], shiftF[t]), 0.f);
                zrow[(quad * 4 + r) * 72 + t * 16 + n16] = f2bf(z);
            }
        }
        __threadfence_block();
        bf16x8 az0 = *(const bf16x8*)&zrow[n16 * 72 + quad * 8];
        bf16x8 az1 = *(const bf16x8*)&zrow[n16 * 72 + 32 + quad * 8];

        f32x4 acc2[4];
#pragma unroll
        for (int t = 0; t < 4; ++t) {
            f32x4 z4 = {0.f, 0.f, 0.f, 0.f};
            z4 = __builtin_amdgcn_mfma_f32_16x16x32_bf16(az0, w2f[t][0], z4, 0, 0, 0);
            z4 = __builtin_amdgcn_mfma_f32_16x16x32_bf16(az1, w2f[t][1], z4, 0, 0, 0);
            acc2[t] = z4;
        }
#pragma unroll
        for (int t = 0; t < 4; ++t) {
#pragma unroll
            for (int r = 0; r < 4; ++r) {
                float h = fmaxf(acc2[t][r] + b2F[t], 0.f);
                hout[(size_t)(nodebase + quad * 4 + r) * 64 + t * 16 + n16] = f2bf(h);
            }
        }
        __threadfence_block();
    }
}

// ---------------- pooling: one wave per (layer, 64-node chunk) ----------------
__launch_bounds__(256)
__global__ void pool_kernel(const unsigned short* __restrict__ h1,
                            const unsigned short* __restrict__ h2,
                            const unsigned short* __restrict__ h3,
                            const int* __restrict__ batch,
                            float* __restrict__ pool) {
    int task = blockIdx.x * 4 + (threadIdx.x >> 6);
    if (task >= NPTASK) return;
    int lane = threadIdx.x & 63;
    int layer = task / NCHUNK;
    int c = task - layer * NCHUNK;
    int n0 = c * 64;
    int n1 = n0 + 64; if (n1 > NNODES) n1 = NNODES;
    const unsigned short* hb = (layer == 0) ? h1 : (layer == 1) ? h2 : h3;
    float acc = 0.f;
    int curg = batch[n0];
    for (int n = n0; n < n1; ++n) {
        int gid = batch[n];
        if (gid != curg) {
            atomicAdd(&pool[(size_t)curg * 192 + layer * 64 + lane], acc);
            acc = 0.f;
            curg = gid;
        }
        acc += bf2f(hb[(size_t)n * 64 + lane]);
    }
    atomicAdd(&pool[(size_t)curg * 192 + layer * 64 + lane], acc);
}

// ---------------- FC head on pooled features ----------------
__global__ void head_kernel(const float* __restrict__ pool,
                            const float* __restrict__ fc1W, const float* __restrict__ fc1b,
                            const float* __restrict__ fc2W, const float* __restrict__ fc2b,
                            float* __restrict__ out) {
    __shared__ float ps[192];
    __shared__ float hs[192];
    int gi = blockIdx.x;
    int t = threadIdx.x;  // 192
    ps[t] = pool[gi * 192 + t];
    __syncthreads();
    float acc = fc1b[t];
#pragma unroll 8
    for (int k = 0; k < 192; ++k) acc = fmaf(ps[k], fc1W[k * 192 + t], acc);
    hs[t] = fmaxf(acc, 0.f);
    __syncthreads();
    if (t == 0) {
        float l0 = fc2b[0], l1 = fc2b[1];
        for (int k = 0; k < 192; ++k) {
            float h = hs[k];
            l0 = fmaf(h, fc2W[k * 2 + 0], l0);
            l1 = fmaf(h, fc2W[k * 2 + 1], l1);
        }
        float mx = fmaxf(l0, l1);
        float lse = mx + logf(expf(l0 - mx) + expf(l1 - mx));
        out[gi * 2 + 0] = l0 - lse;
        out[gi * 2 + 1] = l1 - lse;
    }
}

extern "C" void kernel_launch(void* const* d_in, const int* in_sizes, int n_in,
                              void* d_out, int out_size, void* d_ws, size_t ws_size,
                              hipStream_t stream) {
    const float* x = (const float*)d_in[0];
    const int* src = (const int*)d_in[1];
    const int* dst = (const int*)d_in[2];
    const int* batch = (const int*)d_in[3];
    const float* c1[8];
    const float* c2[8];
    const float* c3[8];
    for (int i = 0; i < 8; ++i) {
        c1[i] = (const float*)d_in[4 + i];
        c2[i] = (const float*)d_in[12 + i];
        c3[i] = (const float*)d_in[20 + i];
    }
    const float* fc1W = (const float*)d_in[28];
    const float* fc1b = (const float*)d_in[29];
    const float* fc2W = (const float*)d_in[30];
    const float* fc2b = (const float*)d_in[31];
    float* out = (float*)d_out;

    // ---- workspace layout (all bf16 activations) ----
    unsigned short* base = (unsigned short*)d_ws;
    const size_t NA = (size_t)NNODES * 64;
    unsigned short* ybf = base;                          // N*64
    unsigned short* xbf = ybf + NA;                      // N*16
    unsigned short* h1  = xbf + (size_t)NNODES * NFP;    // N*64
    unsigned short* h2  = h1 + NA;                       // N*64
    unsigned short* h3  = h2 + NA;                       // N*64
    unsigned short* wfrag = h3 + NA;                     // 3*8192 (16B-aligned)
    float* pool = (float*)(wfrag + 3 * 8192);            // G*192 fp32
    int* ibase = (int*)(pool + (size_t)NG * 192);
    int* cursor  = ibase;                             // N
    int* gcount  = ibase + NNODES;                    // NBUCK
    int* csr     = gcount + NBUCK;                    // N*CAP (+pad)
    int* pairbuf = csr + (size_t)NNODES * CAP + 256;  // NBUCK*RCAP

    hipMemsetAsync(gcount, 0, NBUCK * sizeof(int), stream);
    hipMemsetAsync(pool, 0, (size_t)NG * 192 * sizeof(float), stream);

    // ---- build padded CSR via 2-phase bucket partition + LDS-cursor scatter ----
    cvt_x_kernel<<<2048, 256, 0, stream>>>(x, xbf);
    build_frags_kernel<<<12, 256, 0, stream>>>(c1[0], c1[6], c2[0], c2[6], c3[0], c3[6], wfrag);
    partition_kernel<<<NPBLK, 256, 0, stream>>>(src, dst, gcount, pairbuf);
    bucket_scatter_kernel<<<NBUCK, 512, 0, stream>>>(pairbuf, gcount, cursor, csr);

    const int AGG_BLOCKS = 25000;  // 4 waves/block -> one wave per node
    const int MLP_BLOCKS = 1024;

    // ---- layer 1 (fin=13, 32 B rows): 16 edges/gather; MFMA MLP with K=32 (1 chunk) ----
    agg_vec_kernel<NFP, 4, 2, 1><<<AGG_BLOCKS, 256, 0, stream>>>(xbf, cursor, csr, ybf);
    mlp_mfma_kernel<1><<<MLP_BLOCKS, 256, 0, stream>>>(
        ybf, wfrag + 0 * 8192, c1[1], c1[2], c1[3], c1[4], c1[5], c1[7], h1);

    // ---- layer 2 (fin=64, 128 B rows): 8 edges/gather (16 B lanes); MFMA MLP K=64 ----
    agg_vec8_kernel<<<AGG_BLOCKS, 256, 0, stream>>>(h1, cursor, csr, ybf);
    mlp_mfma_kernel<2><<<MLP_BLOCKS, 256, 0, stream>>>(
        ybf, wfrag + 1 * 8192, c2[1], c2[2], c2[3], c2[4], c2[5], c2[7], h2);

    // ---- layer 3 (fin=64) ----
    agg_vec8_kernel<<<AGG_BLOCKS, 256, 0, stream>>>(h2, cursor, csr, ybf);
    mlp_mfma_kernel<2><<<MLP_BLOCKS, 256, 0, stream>>>(
        ybf, wfrag + 2 * 8192, c3[1], c3[2], c3[3], c3[4], c3[5], c3[7], h3);

    // ---- pooling (one wave per layer-chunk) + FC head ----
    pool_kernel<<<(NPTASK + 3) / 4, 256, 0, stream>>>(h1, h2, h3, batch, pool);
    head_kernel<<<NG, 192, 0, stream>>>(pool, fc1W, fc1b, fc2W, fc2b, out);
}